// Round 5
// baseline (474.758 us; speedup 1.0000x reference)
//
#include <hip/hip_runtime.h>
#include <hip/hip_fp16.h>
#include <math.h>

#define DIM    512
#define NTHR   512
#define NKK    256          // pair-rows (2 matrix rows per pair)
#define SLABKK 70           // pair-rows cached in LDS (70 * 2KB = 140 KB)
#define GI     4            // items per block

typedef _Float16 h2_t __attribute__((ext_vector_type(2)));

#if defined(__has_builtin)
#  if __has_builtin(__builtin_amdgcn_fdot2)
#    define HAVE_FDOT2 1
#  endif
#endif
#ifndef HAVE_FDOT2
#  define HAVE_FDOT2 0
#endif

// acc += C_pair . p_pair (2 MACs, fp32 accumulate)
__device__ __forceinline__ float dot2acc(unsigned int cu, unsigned int pu, float acc) {
#if HAVE_FDOT2
    return __builtin_amdgcn_fdot2(__builtin_bit_cast(h2_t, cu),
                                  __builtin_bit_cast(h2_t, pu), acc, false);
#else
    const float2 cf = __half22float2(*reinterpret_cast<const __half2*>(&cu));
    const float2 pf = __half22float2(*reinterpret_cast<const __half2*>(&pu));
    return fmaf(cf.y, pf.y, fmaf(cf.x, pf.x, acc));
#endif
}

// per-wave partials of 4 values -> dst[wave*4 + m]
__device__ __forceinline__ void wave_part4(float v0, float v1, float v2, float v3,
                                           float* dst) {
    #pragma unroll
    for (int off = 32; off > 0; off >>= 1) {
        v0 += __shfl_down(v0, off, 64);
        v1 += __shfl_down(v1, off, 64);
        v2 += __shfl_down(v2, off, 64);
        v3 += __shfl_down(v3, off, 64);
    }
    if ((threadIdx.x & 63) == 0) {
        const int w4 = (threadIdx.x >> 6) * 4;
        dst[w4 + 0] = v0; dst[w4 + 1] = v1; dst[w4 + 2] = v2; dst[w4 + 3] = v3;
    }
}

__device__ __forceinline__ void sum8x4(const float* src, float out[GI]) {
    #pragma unroll
    for (int m = 0; m < GI; ++m) {
        float s = 0.f;
        #pragma unroll
        for (int w = 0; w < 8; ++w) s += src[w * 4 + m];
        out[m] = s;
    }
}

// w[m][j] = (C p_m)[j], column form: thread j accumulates over all pair-rows.
// C pair-packed: uint at [kk*DIM + j] = half2(C[2kk][j], C[2kk+1][j]).
__device__ __forceinline__ void matvec16_col4(
    const unsigned int* __restrict__ Cg, const unsigned int* C_lds,
    const uint2* ph0, const uint2* ph1, const uint2* ph2, const uint2* ph3,
    int j, float wc[GI])
{
    float a0 = 0.f, a1 = 0.f, a2 = 0.f, a3 = 0.f;
    #pragma unroll 4
    for (int kk2 = 0; kk2 < SLABKK / 2; ++kk2) {          // LDS slab part
        const unsigned int c0 = C_lds[(2 * kk2)     * DIM + j];
        const unsigned int c1 = C_lds[(2 * kk2 + 1) * DIM + j];
        const uint2 q0 = ph0[kk2]; a0 = dot2acc(c1, q0.y, dot2acc(c0, q0.x, a0));
        const uint2 q1 = ph1[kk2]; a1 = dot2acc(c1, q1.y, dot2acc(c0, q1.x, a1));
        const uint2 q2 = ph2[kk2]; a2 = dot2acc(c1, q2.y, dot2acc(c0, q2.x, a2));
        const uint2 q3 = ph3[kk2]; a3 = dot2acc(c1, q3.y, dot2acc(c0, q3.x, a3));
    }
    #pragma unroll 4
    for (int kk2 = SLABKK / 2; kk2 < NKK / 2; ++kk2) {    // L2-streamed part
        const unsigned int c0 = Cg[(2 * kk2)     * DIM + j];
        const unsigned int c1 = Cg[(2 * kk2 + 1) * DIM + j];
        const uint2 q0 = ph0[kk2]; a0 = dot2acc(c1, q0.y, dot2acc(c0, q0.x, a0));
        const uint2 q1 = ph1[kk2]; a1 = dot2acc(c1, q1.y, dot2acc(c0, q1.x, a1));
        const uint2 q2 = ph2[kk2]; a2 = dot2acc(c1, q2.y, dot2acc(c0, q2.x, a2));
        const uint2 q3 = ph3[kk2]; a3 = dot2acc(c1, q3.y, dot2acc(c0, q3.x, a3));
    }
    wc[0] = a0; wc[1] = a1; wc[2] = a2; wc[3] = a3;
}

// fp32 column matvec for the refinement residual (reads fp32 cov0).
__device__ __forceinline__ void matvec32_col4(const float* __restrict__ C,
                                              const float (*p_s)[DIM], int j,
                                              float w[GI]) {
    const float2* ps0 = reinterpret_cast<const float2*>(p_s[0]);
    const float2* ps1 = reinterpret_cast<const float2*>(p_s[1]);
    const float2* ps2 = reinterpret_cast<const float2*>(p_s[2]);
    const float2* ps3 = reinterpret_cast<const float2*>(p_s[3]);
    float a0 = 0.f, a1 = 0.f, a2 = 0.f, a3 = 0.f;
    #pragma unroll 4
    for (int k2 = 0; k2 < DIM / 2; ++k2) {
        const float c0 = C[(2 * k2)     * DIM + j];
        const float c1 = C[(2 * k2 + 1) * DIM + j];
        const float2 q0 = ps0[k2]; a0 = fmaf(c1, q0.y, fmaf(c0, q0.x, a0));
        const float2 q1 = ps1[k2]; a1 = fmaf(c1, q1.y, fmaf(c0, q1.x, a1));
        const float2 q2 = ps2[k2]; a2 = fmaf(c1, q2.y, fmaf(c0, q2.x, a2));
        const float2 q3 = ps3[k2]; a3 = fmaf(c1, q3.y, fmaf(c0, q3.x, a3));
    }
    w[0] = a0; w[1] = a1; w[2] = a2; w[3] = a3;
}

// 4-item batched CG on (a2_m C16 + s2_m I) x = b_m with EXPLICIT residual norms
// (robust to fp16-p matvec noise — the round-3 failure mode). 3 barriers/iter.
__device__ void cg4(const float bj[GI], const float a2v[GI], const float s2v[GI],
                    const unsigned int* __restrict__ Cg, const unsigned int* C_lds,
                    float (*p_s)[DIM], unsigned short (*p_h)[DIM],
                    float* red1, float* red2, int maxit, float tolf, float xout[GI])
{
    const int tid = threadIdx.x;
    const uint2* ph0 = reinterpret_cast<const uint2*>(p_h[0]);
    const uint2* ph1 = reinterpret_cast<const uint2*>(p_h[1]);
    const uint2* ph2 = reinterpret_cast<const uint2*>(p_h[2]);
    const uint2* ph3 = reinterpret_cast<const uint2*>(p_h[3]);

    float xj[GI], rj[GI], pj[GI], rs[GI], tol[GI];

    __syncthreads();   // entry fence: prior phase's readers of p_s/p_h/red2 done
    #pragma unroll
    for (int m = 0; m < GI; ++m) {
        xj[m] = 0.f; rj[m] = bj[m]; pj[m] = bj[m];
        p_s[m][tid] = pj[m];
        p_h[m][tid] = __half_as_ushort(__float2half(pj[m]));
    }
    wave_part4(rj[0]*rj[0], rj[1]*rj[1], rj[2]*rj[2], rj[3]*rj[3], red2);
    __syncthreads();   // publishes p_s/p_h + red2
    {
        float t4[GI]; sum8x4(red2, t4);
        #pragma unroll
        for (int m = 0; m < GI; ++m) { rs[m] = t4[m]; tol[m] = tolf * t4[m]; }
    }

    for (int it = 0; it < maxit; ++it) {
        float wc[GI];
        matvec16_col4(Cg, C_lds, ph0, ph1, ph2, ph3, tid, wc);
        float wj[GI], pwp[GI];
        #pragma unroll
        for (int m = 0; m < GI; ++m) {
            wj[m]  = fmaf(a2v[m], wc[m], s2v[m] * pj[m]);
            pwp[m] = pj[m] * wj[m];
        }
        wave_part4(pwp[0], pwp[1], pwp[2], pwp[3], red1);
        __syncthreads();                                   // A
        float pw[GI]; sum8x4(red1, pw);
        bool act[GI];
        #pragma unroll
        for (int m = 0; m < GI; ++m) {
            act[m] = rs[m] > tol[m];
            const float alpha = act[m] ? rs[m] / fmaxf(pw[m], 1e-30f) : 0.f;
            xj[m] = fmaf( alpha, pj[m], xj[m]);
            rj[m] = fmaf(-alpha, wj[m], rj[m]);
        }
        wave_part4(rj[0]*rj[0], rj[1]*rj[1], rj[2]*rj[2], rj[3]*rj[3], red2);
        __syncthreads();                                   // B
        float rsn[GI]; sum8x4(red2, rsn);
        bool cont = false;
        #pragma unroll
        for (int m = 0; m < GI; ++m) {
            if (act[m]) {
                const float bet = rsn[m] / fmaxf(rs[m], 1e-30f);
                if (rsn[m] > tol[m]) {           // uniform per item
                    pj[m] = fmaf(bet, pj[m], rj[m]);
                    p_s[m][tid] = pj[m];
                    p_h[m][tid] = __half_as_ushort(__float2half(pj[m]));
                }
                rs[m] = rsn[m];
            }
            if (rs[m] > tol[m]) cont = true;
        }
        if (!cont) break;                                  // uniform
        __syncthreads();                                   // C: publish p
    }
    #pragma unroll
    for (int m = 0; m < GI; ++m) xout[m] = xj[m];
}

// ---------- main solver: 4 items per block ----------
__global__ __launch_bounds__(NTHR, 1)
void vps_solve4_kernel(const float* __restrict__ t_arr,
                       const float* __restrict__ x_arr,
                       const float* __restrict__ mean0,
                       const float* __restrict__ cov0,
                       const unsigned int* __restrict__ Cp,
                       float* __restrict__ out)
{
    __shared__ unsigned int C_lds[SLABKK * DIM];           // 140 KB
    __shared__ __align__(16) float p_s[GI][DIM];           // 8 KB
    __shared__ __align__(8)  unsigned short p_h[GI][DIM];  // 4 KB
    __shared__ float red1[32];
    __shared__ float red2[32];

    const int b0  = blockIdx.x * GI;
    const int tid = threadIdx.x;

    float av[GI], a2v[GI], s2v[GI];
    #pragma unroll
    for (int m = 0; m < GI; ++m) {
        const float t  = t_arr[b0 + m];
        const float ib = 0.1f * t + 9.95f * t * t;
        av[m]  = expf(-0.5f * ib);
        a2v[m] = av[m] * av[m];
        s2v[m] = fmaxf(1.0f - a2v[m], 1e-12f);
    }
    const float mu = mean0[tid];
    float rhs[GI];
    #pragma unroll
    for (int m = 0; m < GI; ++m)
        rhs[m] = x_arr[(b0 + m) * DIM + tid] - av[m] * mu;

    {   // load slab (coalesced uint4)
        const uint4* src = reinterpret_cast<const uint4*>(Cp);
        uint4* dst = reinterpret_cast<uint4*>(C_lds);
        for (int i = tid; i < SLABKK * DIM / 4; i += NTHR) dst[i] = src[i];
    }
    // cg4's internal barriers make the slab visible before the first matvec.

    // Phase 1: CG on fp16 matrix
    float x1[GI];
    cg4(rhs, a2v, s2v, Cp, C_lds, p_s, p_h, red1, red2, 26, 1e-4f, x1);

    // Exact fp32 residual
    __syncthreads();
    #pragma unroll
    for (int m = 0; m < GI; ++m) p_s[m][tid] = x1[m];
    __syncthreads();
    float cw[GI];
    matvec32_col4(cov0, p_s, tid, cw);
    float rt[GI];
    #pragma unroll
    for (int m = 0; m < GI; ++m)
        rt[m] = rhs[m] - (a2v[m] * cw[m] + s2v[m] * x1[m]);

    // Phase 2: correction solve (absorbs fp16 matrix + fp16-p perturbation)
    float z[GI];
    cg4(rt, a2v, s2v, Cp, C_lds, p_s, p_h, red1, red2, 26, 1e-4f, z);

    #pragma unroll
    for (int m = 0; m < GI; ++m)
        out[(b0 + m) * DIM + tid] = -(x1[m] + z[m]);
}

// ---------- pack cov0 -> pair-interleaved fp16: out[kk*512+j] = half2(C[2kk][j], C[2kk+1][j]) ----------
__global__ void conv_pack_kernel(const float* __restrict__ C, unsigned int* __restrict__ out) {
    const int id = blockIdx.x * 256 + threadIdx.x;   // 131072 total
    const int kk = id >> 9;
    const int j  = id & 511;
    const __half2 h = __floats2half2_rn(C[(2 * kk) * DIM + j], C[(2 * kk + 1) * DIM + j]);
    out[id] = *reinterpret_cast<const unsigned int*>(&h);
}

// ================= fallback path (ws too small): round-4-proven fp32 CG =================
__device__ __forceinline__ float block_reduce_sum(float v, float* red) {
    #pragma unroll
    for (int off = 32; off > 0; off >>= 1) v += __shfl_down(v, off, 64);
    const int wid = threadIdx.x >> 6, lane = threadIdx.x & 63;
    __syncthreads();
    if (lane == 0) red[wid] = v;
    __syncthreads();
    float s = 0.f;
    #pragma unroll
    for (int i = 0; i < 8; ++i) s += red[i];
    return s;
}

__device__ __forceinline__ float matvec_assemble(float4 acc, float4* part, float4* w4_s) {
    const int tid = threadIdx.x;
    __syncthreads();
    part[tid] = acc;
    __syncthreads();
    if (tid < 128) {
        const float4 a0 = part[tid], a1 = part[tid + 128];
        const float4 a2 = part[tid + 256], a3 = part[tid + 384];
        float4 s4;
        s4.x = (a0.x + a1.x) + (a2.x + a3.x);
        s4.y = (a0.y + a1.y) + (a2.y + a3.y);
        s4.z = (a0.z + a1.z) + (a2.z + a3.z);
        s4.w = (a0.w + a1.w) + (a2.w + a3.w);
        w4_s[tid] = s4;
    }
    __syncthreads();
    return reinterpret_cast<const float*>(w4_s)[tid];
}

__device__ __forceinline__ float matvec32(const float4* __restrict__ Cq, const float* p_s,
                                          float4* part, float4* w4_s) {
    const int tid = threadIdx.x;
    const int g = tid >> 7, jq = tid & 127;
    float4 acc = make_float4(0.f, 0.f, 0.f, 0.f);
    int idx = g * 128 + jq;
    #pragma unroll 8
    for (int k = g; k < DIM; k += 4) {
        const float4 cv = Cq[idx];
        const float  pk = p_s[k];
        acc.x = fmaf(pk, cv.x, acc.x);
        acc.y = fmaf(pk, cv.y, acc.y);
        acc.z = fmaf(pk, cv.z, acc.z);
        acc.w = fmaf(pk, cv.w, acc.w);
        idx += 512;
    }
    return matvec_assemble(acc, part, w4_s);
}

__global__ __launch_bounds__(NTHR, 1)
void vps_cg_kernel(const float* __restrict__ t_arr, const float* __restrict__ x_arr,
                   const float* __restrict__ mean0, const float* __restrict__ cov0,
                   float* __restrict__ out)
{
    const int b = blockIdx.x, tid = threadIdx.x;
    __shared__ float4 part[NTHR];
    __shared__ float4 p4_s[DIM / 4];
    __shared__ float4 w4_s[DIM / 4];
    __shared__ float  red[16];
    float* p_s = (float*)p4_s;
    const float t  = t_arr[b];
    const float ib = 0.1f * t + 9.95f * t * t;
    const float a  = expf(-0.5f * ib);
    const float a2 = a * a;
    const float s2 = fmaxf(1.0f - a2, 1e-12f);
    const float rhs = x_arr[b * DIM + tid] - a * mean0[tid];
    float xj = 0.f, rj = rhs, pj = rhs;
    p_s[tid] = pj;
    float rs = block_reduce_sum(rj * rj, red);
    const float tol = rs * 1e-12f;
    for (int it = 0; it < 72; ++it) {
        const float cw = matvec32(reinterpret_cast<const float4*>(cov0), p_s, part, w4_s);
        const float wj = a2 * cw + s2 * pj;
        const float pw = block_reduce_sum(pj * wj, red);
        const float alpha = rs / fmaxf(pw, 1e-37f);
        xj = fmaf(alpha, pj, xj);
        rj = fmaf(-alpha, wj, rj);
        const float rsn = block_reduce_sum(rj * rj, red);
        if (rsn < tol) break;
        const float beta = rsn / fmaxf(rs, 1e-37f);
        pj = fmaf(beta, pj, rj);
        rs = rsn;
        p_s[tid] = pj;
        __syncthreads();
    }
    out[b * DIM + tid] = -xj;
}

extern "C" void kernel_launch(void* const* d_in, const int* in_sizes, int n_in,
                              void* d_out, int out_size, void* d_ws, size_t ws_size,
                              hipStream_t stream) {
    const float* t_arr = (const float*)d_in[0];
    const float* x_arr = (const float*)d_in[1];
    const float* m0    = (const float*)d_in[2];
    const float* c0    = (const float*)d_in[3];
    float* out = (float*)d_out;
    const int B = in_sizes[0];   // 128
    const size_t need = (size_t)NKK * DIM * 4;   // 512 KB packed fp16
    if (ws_size >= need && (B % GI) == 0) {
        hipLaunchKernelGGL(conv_pack_kernel, dim3(NKK * DIM / 256), dim3(256), 0, stream,
                           c0, (unsigned int*)d_ws);
        hipLaunchKernelGGL(vps_solve4_kernel, dim3(B / GI), dim3(NTHR), 0, stream,
                           t_arr, x_arr, m0, c0, (const unsigned int*)d_ws, out);
    } else {
        hipLaunchKernelGGL(vps_cg_kernel, dim3(B), dim3(NTHR), 0, stream,
                           t_arr, x_arr, m0, c0, out);
    }
}

// Round 6
// 167.731 us; speedup vs baseline: 2.8305x; 2.8305x over previous
//
#include <hip/hip_runtime.h>
#include <hip/hip_fp16.h>
#include <math.h>

#define DIM    512
#define NTHR   512
#define NKK    256          // pair-rows (2 matrix rows per pair)
#define SLABKK 68           // pair-rows in LDS (68 * 2KB = 136 KB); % 4 == 0

typedef _Float16 h2_t __attribute__((ext_vector_type(2)));

#if defined(__has_builtin)
#  if __has_builtin(__builtin_amdgcn_fdot2)
#    define HAVE_FDOT2 1
#  endif
#endif
#ifndef HAVE_FDOT2
#  define HAVE_FDOT2 0
#endif

// acc += C_pair . p_pair (2 MACs, fp32 accumulate) — round-5-proven numerics
__device__ __forceinline__ float dot2acc(unsigned int cu, unsigned int pu, float acc) {
#if HAVE_FDOT2
    return __builtin_amdgcn_fdot2(__builtin_bit_cast(h2_t, cu),
                                  __builtin_bit_cast(h2_t, pu), acc, false);
#else
    const float2 cf = __half22float2(*reinterpret_cast<const __half2*>(&cu));
    const float2 pf = __half22float2(*reinterpret_cast<const __half2*>(&pu));
    return fmaf(cf.y, pf.y, fmaf(cf.x, pf.x, acc));
#endif
}

// ---------- 8-wave block sum (phase init only) ----------
__device__ __forceinline__ float block_reduce_sum(float v, float* red) {
    #pragma unroll
    for (int off = 32; off > 0; off >>= 1) v += __shfl_down(v, off, 64);
    const int wid = threadIdx.x >> 6, lane = threadIdx.x & 63;
    __syncthreads();
    if (lane == 0) red[wid] = v;
    __syncthreads();
    float s = 0.f;
    #pragma unroll
    for (int i = 0; i < 8; ++i) s += red[i];
    return s;
}

// ---------- fp32 matvec (refinement residual), round-4-proven ----------
__device__ __forceinline__ float matvec_assemble(float4 acc, float4* part, float4* w4_s) {
    const int tid = threadIdx.x;
    __syncthreads();
    part[tid] = acc;
    __syncthreads();
    if (tid < 128) {
        const float4 a0 = part[tid], a1 = part[tid + 128];
        const float4 a2 = part[tid + 256], a3 = part[tid + 384];
        float4 s4;
        s4.x = (a0.x + a1.x) + (a2.x + a3.x);
        s4.y = (a0.y + a1.y) + (a2.y + a3.y);
        s4.z = (a0.z + a1.z) + (a2.z + a3.z);
        s4.w = (a0.w + a1.w) + (a2.w + a3.w);
        w4_s[tid] = s4;
    }
    __syncthreads();
    return reinterpret_cast<const float*>(w4_s)[tid];
}

__device__ __forceinline__ float matvec32(const float4* __restrict__ Cq, const float* p_s,
                                          float4* part, float4* w4_s) {
    const int tid = threadIdx.x;
    const int g = tid >> 7, jq = tid & 127;
    float4 acc = make_float4(0.f, 0.f, 0.f, 0.f);
    int idx = g * 128 + jq;
    #pragma unroll 8
    for (int k = g; k < DIM; k += 4) {
        const float4 cv = Cq[idx];
        const float  pk = p_s[k];
        acc.x = fmaf(pk, cv.x, acc.x);
        acc.y = fmaf(pk, cv.y, acc.y);
        acc.z = fmaf(pk, cv.z, acc.z);
        acc.w = fmaf(pk, cv.w, acc.w);
        idx += 512;
    }
    return matvec_assemble(acc, part, w4_s);
}

// ---------- pair-packed fdot2 matvec body ----------
// Cp layout: uint at [kk*DIM + j] = half2(C[2kk][j], C[2kk+1][j]);
// uint4 at quad index [kk*128 + jq] = cols 4jq..4jq+3 of pair-row kk.
// Thread (g, jq) covers cols 4jq..4jq+3, pair-rows kk ≡ g (mod 4).
__device__ __forceinline__ float4 matvec16_body(const uint4* __restrict__ Cg,
                                                const uint4* C_lds,
                                                const unsigned int* p_h32,
                                                int g, int jq) {
    float4 acc = make_float4(0.f, 0.f, 0.f, 0.f);
    int idx = g * 128 + jq;
    #pragma unroll 4
    for (int kk = g; kk < SLABKK; kk += 4) {      // 17 steps from LDS
        const uint4 cv = C_lds[idx];
        const unsigned int pu = p_h32[kk];        // wave-uniform broadcast
        acc.x = dot2acc(cv.x, pu, acc.x);
        acc.y = dot2acc(cv.y, pu, acc.y);
        acc.z = dot2acc(cv.z, pu, acc.z);
        acc.w = dot2acc(cv.w, pu, acc.w);
        idx += 512;                               // 4 pair-rows of 128 quads
    }
    idx = (SLABKK + g) * 128 + jq;
    #pragma unroll 4
    for (int kk = SLABKK + g; kk < NKK; kk += 4) { // 47 steps from L2, 16B/lane
        const uint4 cv = Cg[idx];
        const unsigned int pu = p_h32[kk];
        acc.x = dot2acc(cv.x, pu, acc.x);
        acc.y = dot2acc(cv.y, pu, acc.y);
        acc.z = dot2acc(cv.z, pu, acc.z);
        acc.w = dot2acc(cv.w, pu, acc.w);
        idx += 512;
    }
    return acc;
}

// ---------- CG phase: fdot2 matvec, fp16 p, EXPLICIT residual, 4 barriers/iter ----------
__device__ float cg_phase(float bj, float a2, float s2,
                          const uint4* __restrict__ Cg, const uint4* C_lds,
                          float* p_s, unsigned short* p_h, float* w_s,
                          float4* part, float* red1, float* red2,
                          int maxit, float tolf)
{
    const int tid = threadIdx.x;
    const int g   = tid >> 7;
    const int jq  = tid & 127;
    const unsigned int* p_h32 = (const unsigned int*)p_h;

    float xj = 0.f, rj = bj, pj = bj;
    __syncthreads();                   // entry fence: prior readers of p_s/p_h done
    p_s[tid] = pj;
    p_h[tid] = __half_as_ushort(__float2half(pj));
    float rs = block_reduce_sum(rj * rj, red2);   // internal barriers publish p
    if (!(rs > 0.f)) return xj;                   // uniform
    const float tol = tolf * rs;

    for (int it = 0; it < maxit; ++it) {
        const float4 acc = matvec16_body(Cg, C_lds, p_h32, g, jq);
        part[tid] = acc;
        __syncthreads();                                   // A: part published
        if (tid < 128) {
            const float4 a0 = part[tid],       a1 = part[tid + 128];
            const float4 b2 = part[tid + 256], a3 = part[tid + 384];
            float4 cw;
            cw.x = (a0.x + a1.x) + (b2.x + a3.x);
            cw.y = (a0.y + a1.y) + (b2.y + a3.y);
            cw.z = (a0.z + a1.z) + (b2.z + a3.z);
            cw.w = (a0.w + a1.w) + (b2.w + a3.w);
            const float4 p4 = reinterpret_cast<const float4*>(p_s)[tid];
            float4 w4;
            w4.x = fmaf(a2, cw.x, s2 * p4.x);
            w4.y = fmaf(a2, cw.y, s2 * p4.y);
            w4.z = fmaf(a2, cw.z, s2 * p4.z);
            w4.w = fmaf(a2, cw.w, s2 * p4.w);
            reinterpret_cast<float4*>(w_s)[tid] = w4;
            float pwp = p4.x*w4.x + p4.y*w4.y + p4.z*w4.z + p4.w*w4.w;
            #pragma unroll
            for (int off = 32; off > 0; off >>= 1) pwp += __shfl_down(pwp, off, 64);
            if ((tid & 63) == 0) red1[tid >> 6] = pwp;
        }
        __syncthreads();                                   // B: w_s + pw published
        const float pw    = fmaxf(red1[0] + red1[1], 1e-30f);
        const float alpha = rs / pw;
        const float wj    = w_s[tid];
        xj = fmaf( alpha, pj, xj);
        rj = fmaf(-alpha, wj, rj);
        {   // explicit ||r||^2 (robust to fp16-p matvec noise)
            float rr = rj * rj;
            #pragma unroll
            for (int off = 32; off > 0; off >>= 1) rr += __shfl_down(rr, off, 64);
            if ((tid & 63) == 0) red2[tid >> 6] = rr;
        }
        __syncthreads();                                   // C: r^2 partials
        float rsn = 0.f;
        #pragma unroll
        for (int i = 0; i < 8; ++i) rsn += red2[i];
        if (!(rsn > tol)) break;                           // uniform
        const float beta = rsn / rs;
        rs = rsn;
        pj = fmaf(beta, pj, rj);
        p_s[tid] = pj;
        p_h[tid] = __half_as_ushort(__float2half(pj));
        __syncthreads();                                   // D: p published
    }
    return xj;
}

// ---------- main solver: one block per item ----------
__global__ __launch_bounds__(NTHR, 1)
void vps_solve_kernel(const float* __restrict__ t_arr,
                      const float* __restrict__ x_arr,
                      const float* __restrict__ mean0,
                      const float* __restrict__ cov0,
                      const uint4* __restrict__ Cp,
                      float* __restrict__ out)
{
    __shared__ uint4  C_lds[SLABKK * 128];                 // 136 KB slab
    __shared__ float4 part[NTHR];                          // 8 KB
    __shared__ float4 p4_s[DIM / 4];                       // 2 KB
    __shared__ float4 w4_s[DIM / 4];                       // 2 KB
    __shared__ __align__(4) unsigned short p_h[DIM];       // 1 KB
    __shared__ float  red1[8];
    __shared__ float  red2[8];
    float* p_s = (float*)p4_s;
    float* w_s = (float*)w4_s;

    const int b   = blockIdx.x;
    const int tid = threadIdx.x;

    const float t  = t_arr[b];
    const float ib = 0.1f * t + 9.95f * t * t;
    const float a  = expf(-0.5f * ib);
    const float a2 = a * a;
    const float s2 = fmaxf(1.0f - a2, 1e-12f);

    const float rhs = x_arr[b * DIM + tid] - a * mean0[tid];

    // load slab once (coalesced uint4; 17 per thread)
    for (int i = tid; i < SLABKK * 128; i += NTHR) C_lds[i] = Cp[i];
    // cg_phase's entry barriers make the slab visible before the first matvec.

    // Phase 1: CG on fp16 pair-packed matrix
    const float x1 = cg_phase(rhs, a2, s2, Cp, C_lds, p_s, p_h, w_s, part,
                              red1, red2, 24, 1e-4f);

    // Exact fp32 residual
    __syncthreads();
    p_s[tid] = x1;
    __syncthreads();
    const float cw  = matvec32(reinterpret_cast<const float4*>(cov0), p_s, part, w4_s);
    const float rtj = rhs - (a2 * cw + s2 * x1);

    // Phase 2: correction solve (absorbs fp16 matrix + fp16-p perturbation)
    const float z = cg_phase(rtj, a2, s2, Cp, C_lds, p_s, p_h, w_s, part,
                             red1, red2, 24, 1e-4f);

    out[b * DIM + tid] = -(x1 + z);
}

// ---------- pack cov0 -> pair-interleaved fp16 (round-5 proven) ----------
__global__ void conv_pack_kernel(const float* __restrict__ C, unsigned int* __restrict__ out) {
    const int id = blockIdx.x * 256 + threadIdx.x;   // 131072 total
    const int kk = id >> 9;
    const int j  = id & 511;
    const __half2 h = __floats2half2_rn(C[(2 * kk) * DIM + j], C[(2 * kk + 1) * DIM + j]);
    out[id] = *reinterpret_cast<const unsigned int*>(&h);
}

// ================= fallback path (ws too small): round-4-proven fp32 CG =================
__global__ __launch_bounds__(NTHR, 1)
void vps_cg_kernel(const float* __restrict__ t_arr, const float* __restrict__ x_arr,
                   const float* __restrict__ mean0, const float* __restrict__ cov0,
                   float* __restrict__ out)
{
    const int b = blockIdx.x, tid = threadIdx.x;
    __shared__ float4 part[NTHR];
    __shared__ float4 p4_s[DIM / 4];
    __shared__ float4 w4_s[DIM / 4];
    __shared__ float  red[16];
    float* p_s = (float*)p4_s;
    const float t  = t_arr[b];
    const float ib = 0.1f * t + 9.95f * t * t;
    const float a  = expf(-0.5f * ib);
    const float a2 = a * a;
    const float s2 = fmaxf(1.0f - a2, 1e-12f);
    const float rhs = x_arr[b * DIM + tid] - a * mean0[tid];
    float xj = 0.f, rj = rhs, pj = rhs;
    p_s[tid] = pj;
    float rs = block_reduce_sum(rj * rj, red);
    const float tol = rs * 1e-12f;
    for (int it = 0; it < 72; ++it) {
        const float cw = matvec32(reinterpret_cast<const float4*>(cov0), p_s, part, w4_s);
        const float wj = a2 * cw + s2 * pj;
        const float pw = block_reduce_sum(pj * wj, red);
        const float alpha = rs / fmaxf(pw, 1e-37f);
        xj = fmaf(alpha, pj, xj);
        rj = fmaf(-alpha, wj, rj);
        const float rsn = block_reduce_sum(rj * rj, red);
        if (rsn < tol) break;
        const float beta = rsn / fmaxf(rs, 1e-37f);
        pj = fmaf(beta, pj, rj);
        rs = rsn;
        p_s[tid] = pj;
        __syncthreads();
    }
    out[b * DIM + tid] = -xj;
}

extern "C" void kernel_launch(void* const* d_in, const int* in_sizes, int n_in,
                              void* d_out, int out_size, void* d_ws, size_t ws_size,
                              hipStream_t stream) {
    const float* t_arr = (const float*)d_in[0];
    const float* x_arr = (const float*)d_in[1];
    const float* m0    = (const float*)d_in[2];
    const float* c0    = (const float*)d_in[3];
    float* out = (float*)d_out;
    const int B = in_sizes[0];   // 128
    const size_t need = (size_t)NKK * DIM * 4;   // 512 KB packed fp16
    if (ws_size >= need) {
        hipLaunchKernelGGL(conv_pack_kernel, dim3(NKK * DIM / 256), dim3(256), 0, stream,
                           c0, (unsigned int*)d_ws);
        hipLaunchKernelGGL(vps_solve_kernel, dim3(B), dim3(NTHR), 0, stream,
                           t_arr, x_arr, m0, c0, (const uint4*)d_ws, out);
    } else {
        hipLaunchKernelGGL(vps_cg_kernel, dim3(B), dim3(NTHR), 0, stream,
                           t_arr, x_arr, m0, c0, out);
    }
}

// Round 7
// 153.997 us; speedup vs baseline: 3.0829x; 1.0892x over previous
//
#include <hip/hip_runtime.h>
#include <hip/hip_fp16.h>
#include <math.h>

#define DIM    512
#define NTHR   512
#define NKK    256          // pair-rows (2 matrix rows per pair)
#define SLABKK 72           // pair-rows in LDS (72 * 2KB = 144 KB); % 8 == 0
#define MM     (DIM / 4)    // 128 pair-pair steps

typedef _Float16 h2_t __attribute__((ext_vector_type(2)));

#if defined(__has_builtin)
#  if __has_builtin(__builtin_amdgcn_fdot2)
#    define HAVE_FDOT2 1
#  endif
#endif
#ifndef HAVE_FDOT2
#  define HAVE_FDOT2 0
#endif

// acc += C_pair . p_pair (2 MACs, fp32 accumulate) — proven numerics
__device__ __forceinline__ float dot2acc(unsigned int cu, unsigned int pu, float acc) {
#if HAVE_FDOT2
    return __builtin_amdgcn_fdot2(__builtin_bit_cast(h2_t, cu),
                                  __builtin_bit_cast(h2_t, pu), acc, false);
#else
    const float2 cf = __half22float2(*reinterpret_cast<const __half2*>(&cu));
    const float2 pf = __half22float2(*reinterpret_cast<const __half2*>(&pu));
    return fmaf(cf.y, pf.y, fmaf(cf.x, pf.x, acc));
#endif
}

// ---------- 8-wave block sum (phase init only) ----------
__device__ __forceinline__ float block_reduce_sum(float v, float* red) {
    #pragma unroll
    for (int off = 32; off > 0; off >>= 1) v += __shfl_down(v, off, 64);
    const int wid = threadIdx.x >> 6, lane = threadIdx.x & 63;
    __syncthreads();
    if (lane == 0) red[wid] = v;
    __syncthreads();
    float s = 0.f;
    #pragma unroll
    for (int i = 0; i < 8; ++i) s += red[i];
    return s;
}

// ---------- fp32 matvec (refinement residual), proven ----------
__device__ __forceinline__ float matvec_assemble(float4 acc, float4* part, float4* w4_s) {
    const int tid = threadIdx.x;
    __syncthreads();
    part[tid] = acc;
    __syncthreads();
    if (tid < 128) {
        const float4 a0 = part[tid], a1 = part[tid + 128];
        const float4 a2 = part[tid + 256], a3 = part[tid + 384];
        float4 s4;
        s4.x = (a0.x + a1.x) + (a2.x + a3.x);
        s4.y = (a0.y + a1.y) + (a2.y + a3.y);
        s4.z = (a0.z + a1.z) + (a2.z + a3.z);
        s4.w = (a0.w + a1.w) + (a2.w + a3.w);
        w4_s[tid] = s4;
    }
    __syncthreads();
    return reinterpret_cast<const float*>(w4_s)[tid];
}

__device__ __forceinline__ float matvec32(const float4* __restrict__ Cq, const float* p_s,
                                          float4* part, float4* w4_s) {
    const int tid = threadIdx.x;
    const int g = tid >> 7, jq = tid & 127;
    float4 acc = make_float4(0.f, 0.f, 0.f, 0.f);
    int idx = g * 128 + jq;
    #pragma unroll 8
    for (int k = g; k < DIM; k += 4) {
        const float4 cv = Cq[idx];
        const float  pk = p_s[k];
        acc.x = fmaf(pk, cv.x, acc.x);
        acc.y = fmaf(pk, cv.y, acc.y);
        acc.z = fmaf(pk, cv.z, acc.z);
        acc.w = fmaf(pk, cv.w, acc.w);
        idx += 512;
    }
    return matvec_assemble(acc, part, w4_s);
}

// ---------- pair-packed fdot2 matvec body (b64 p-broadcasts) ----------
// Cp layout: uint at [kk*DIM + j] = half2(C[2kk][j], C[2kk+1][j]);
// quad (uint4) index [kk*128 + jq] = cols 4jq..4jq+3 of pair-row kk.
// Pair-pair step m covers pair-rows 2m, 2m+1 (k = 4m..4m+3); thread group
// g handles m ≡ g (mod 4); p read once per step as uint2 (b64 broadcast).
__device__ __forceinline__ float4 matvec16_body(const uint4* __restrict__ Cg,
                                                const uint4* C_lds,
                                                const uint2* p_h64,
                                                int g, int jq) {
    float4 acc = make_float4(0.f, 0.f, 0.f, 0.f);
    #pragma unroll
    for (int m = g; m < SLABKK / 2; m += 4) {        // 9 steps from LDS slab
        const uint4 cv0 = C_lds[(2 * m)     * 128 + jq];
        const uint4 cv1 = C_lds[(2 * m + 1) * 128 + jq];
        const uint2 pu  = p_h64[m];                  // wave-uniform b64 broadcast
        acc.x = dot2acc(cv1.x, pu.y, dot2acc(cv0.x, pu.x, acc.x));
        acc.y = dot2acc(cv1.y, pu.y, dot2acc(cv0.y, pu.x, acc.y));
        acc.z = dot2acc(cv1.z, pu.y, dot2acc(cv0.z, pu.x, acc.z));
        acc.w = dot2acc(cv1.w, pu.y, dot2acc(cv0.w, pu.x, acc.w));
    }
    #pragma unroll
    for (int m = SLABKK / 2 + g; m < MM; m += 4) {   // 23 steps from L2, 32B/lane
        const uint4 cv0 = Cg[(2 * m)     * 128 + jq];
        const uint4 cv1 = Cg[(2 * m + 1) * 128 + jq];
        const uint2 pu  = p_h64[m];
        acc.x = dot2acc(cv1.x, pu.y, dot2acc(cv0.x, pu.x, acc.x));
        acc.y = dot2acc(cv1.y, pu.y, dot2acc(cv0.y, pu.x, acc.y));
        acc.z = dot2acc(cv1.z, pu.y, dot2acc(cv0.z, pu.x, acc.z));
        acc.w = dot2acc(cv1.w, pu.y, dot2acc(cv0.w, pu.x, acc.w));
    }
    return acc;
}

// ---------- CG phase: fdot2 matvec, fp16 p, EXPLICIT residual, 4 barriers/iter ----------
__device__ float cg_phase(float bj, float a2, float s2,
                          const uint4* __restrict__ Cg, const uint4* C_lds,
                          float* p_s, unsigned short* p_h, float* w_s,
                          float4* part, float* red1, float* red2,
                          int maxit, float tolf)
{
    const int tid = threadIdx.x;
    const int g   = tid >> 7;
    const int jq  = tid & 127;
    const uint2* p_h64 = (const uint2*)p_h;

    float xj = 0.f, rj = bj, pj = bj;
    __syncthreads();                   // entry fence: prior readers of p_s/p_h done
    p_s[tid] = pj;
    p_h[tid] = __half_as_ushort(__float2half(pj));
    float rs = block_reduce_sum(rj * rj, red2);   // internal barriers publish p
    if (!(rs > 0.f)) return xj;                   // uniform
    const float tol = tolf * rs;

    for (int it = 0; it < maxit; ++it) {
        const float4 acc = matvec16_body(Cg, C_lds, p_h64, g, jq);
        part[tid] = acc;
        __syncthreads();                                   // A: part published
        if (tid < 128) {
            const float4 a0 = part[tid],       a1 = part[tid + 128];
            const float4 b2 = part[tid + 256], a3 = part[tid + 384];
            float4 cw;
            cw.x = (a0.x + a1.x) + (b2.x + a3.x);
            cw.y = (a0.y + a1.y) + (b2.y + a3.y);
            cw.z = (a0.z + a1.z) + (b2.z + a3.z);
            cw.w = (a0.w + a1.w) + (b2.w + a3.w);
            const float4 p4 = reinterpret_cast<const float4*>(p_s)[tid];
            float4 w4;
            w4.x = fmaf(a2, cw.x, s2 * p4.x);
            w4.y = fmaf(a2, cw.y, s2 * p4.y);
            w4.z = fmaf(a2, cw.z, s2 * p4.z);
            w4.w = fmaf(a2, cw.w, s2 * p4.w);
            reinterpret_cast<float4*>(w_s)[tid] = w4;
            float pwp = p4.x*w4.x + p4.y*w4.y + p4.z*w4.z + p4.w*w4.w;
            #pragma unroll
            for (int off = 32; off > 0; off >>= 1) pwp += __shfl_down(pwp, off, 64);
            if ((tid & 63) == 0) red1[tid >> 6] = pwp;
        }
        __syncthreads();                                   // B: w_s + pw published
        const float pw    = fmaxf(red1[0] + red1[1], 1e-30f);
        const float alpha = rs / pw;
        const float wj    = w_s[tid];
        xj = fmaf( alpha, pj, xj);
        rj = fmaf(-alpha, wj, rj);
        {   // explicit ||r||^2 (robust to fp16-p matvec noise)
            float rr = rj * rj;
            #pragma unroll
            for (int off = 32; off > 0; off >>= 1) rr += __shfl_down(rr, off, 64);
            if ((tid & 63) == 0) red2[tid >> 6] = rr;
        }
        __syncthreads();                                   // C: r^2 partials
        float rsn = 0.f;
        #pragma unroll
        for (int i = 0; i < 8; ++i) rsn += red2[i];
        if (!(rsn > tol)) break;                           // uniform
        const float beta = rsn / rs;
        rs = rsn;
        pj = fmaf(beta, pj, rj);
        p_s[tid] = pj;
        p_h[tid] = __half_as_ushort(__float2half(pj));
        __syncthreads();                                   // D: p published
    }
    return xj;
}

// ---------- main solver: one block per item ----------
__global__ __launch_bounds__(NTHR, 1)
void vps_solve_kernel(const float* __restrict__ t_arr,
                      const float* __restrict__ x_arr,
                      const float* __restrict__ mean0,
                      const float* __restrict__ cov0,
                      const uint4* __restrict__ Cp,
                      float* __restrict__ out)
{
    __shared__ uint4  C_lds[SLABKK * 128];                 // 144 KB slab
    __shared__ float4 part[NTHR];                          // 8 KB
    __shared__ float4 p4_s[DIM / 4];                       // 2 KB
    __shared__ float4 w4_s[DIM / 4];                       // 2 KB
    __shared__ __align__(8) unsigned short p_h[DIM];       // 1 KB
    __shared__ float  red1[8];
    __shared__ float  red2[8];
    float* p_s = (float*)p4_s;
    float* w_s = (float*)w4_s;

    const int b   = blockIdx.x;
    const int tid = threadIdx.x;

    const float t  = t_arr[b];
    const float ib = 0.1f * t + 9.95f * t * t;
    const float a  = expf(-0.5f * ib);
    const float a2 = a * a;
    const float s2 = fmaxf(1.0f - a2, 1e-12f);

    const float rhs = x_arr[b * DIM + tid] - a * mean0[tid];

    // load slab once (coalesced uint4; 18 per thread)
    for (int i = tid; i < SLABKK * 128; i += NTHR) C_lds[i] = Cp[i];
    // cg_phase's entry barriers make the slab visible before the first matvec.

    // Phase 1: CG on fp16 pair-packed matrix (rel-r ~1.6e-2)
    const float x1 = cg_phase(rhs, a2, s2, Cp, C_lds, p_s, p_h, w_s, part,
                              red1, red2, 22, 2.5e-4f);

    // Exact fp32 residual
    __syncthreads();
    p_s[tid] = x1;
    __syncthreads();
    const float cw  = matvec32(reinterpret_cast<const float4*>(cov0), p_s, part, w4_s);
    const float rtj = rhs - (a2 * cw + s2 * x1);

    // Phase 2: correction solve (absorbs fp16 matrix + fp16-p perturbation)
    const float z = cg_phase(rtj, a2, s2, Cp, C_lds, p_s, p_h, w_s, part,
                             red1, red2, 20, 6e-4f);

    out[b * DIM + tid] = -(x1 + z);
}

// ---------- pack cov0 -> pair-interleaved fp16 (proven) ----------
__global__ void conv_pack_kernel(const float* __restrict__ C, unsigned int* __restrict__ out) {
    const int id = blockIdx.x * 256 + threadIdx.x;   // 131072 total
    const int kk = id >> 9;
    const int j  = id & 511;
    const __half2 h = __floats2half2_rn(C[(2 * kk) * DIM + j], C[(2 * kk + 1) * DIM + j]);
    out[id] = *reinterpret_cast<const unsigned int*>(&h);
}

// ================= fallback path (ws too small): proven fp32 CG =================
__global__ __launch_bounds__(NTHR, 1)
void vps_cg_kernel(const float* __restrict__ t_arr, const float* __restrict__ x_arr,
                   const float* __restrict__ mean0, const float* __restrict__ cov0,
                   float* __restrict__ out)
{
    const int b = blockIdx.x, tid = threadIdx.x;
    __shared__ float4 part[NTHR];
    __shared__ float4 p4_s[DIM / 4];
    __shared__ float4 w4_s[DIM / 4];
    __shared__ float  red[16];
    float* p_s = (float*)p4_s;
    const float t  = t_arr[b];
    const float ib = 0.1f * t + 9.95f * t * t;
    const float a  = expf(-0.5f * ib);
    const float a2 = a * a;
    const float s2 = fmaxf(1.0f - a2, 1e-12f);
    const float rhs = x_arr[b * DIM + tid] - a * mean0[tid];
    float xj = 0.f, rj = rhs, pj = rhs;
    p_s[tid] = pj;
    float rs = block_reduce_sum(rj * rj, red);
    const float tol = rs * 1e-12f;
    for (int it = 0; it < 72; ++it) {
        const float cw = matvec32(reinterpret_cast<const float4*>(cov0), p_s, part, w4_s);
        const float wj = a2 * cw + s2 * pj;
        const float pw = block_reduce_sum(pj * wj, red);
        const float alpha = rs / fmaxf(pw, 1e-37f);
        xj = fmaf(alpha, pj, xj);
        rj = fmaf(-alpha, wj, rj);
        const float rsn = block_reduce_sum(rj * rj, red);
        if (rsn < tol) break;
        const float beta = rsn / fmaxf(rs, 1e-37f);
        pj = fmaf(beta, pj, rj);
        rs = rsn;
        p_s[tid] = pj;
        __syncthreads();
    }
    out[b * DIM + tid] = -xj;
}

extern "C" void kernel_launch(void* const* d_in, const int* in_sizes, int n_in,
                              void* d_out, int out_size, void* d_ws, size_t ws_size,
                              hipStream_t stream) {
    const float* t_arr = (const float*)d_in[0];
    const float* x_arr = (const float*)d_in[1];
    const float* m0    = (const float*)d_in[2];
    const float* c0    = (const float*)d_in[3];
    float* out = (float*)d_out;
    const int B = in_sizes[0];   // 128
    const size_t need = (size_t)NKK * DIM * 4;   // 512 KB packed fp16
    if (ws_size >= need) {
        hipLaunchKernelGGL(conv_pack_kernel, dim3(NKK * DIM / 256), dim3(256), 0, stream,
                           c0, (unsigned int*)d_ws);
        hipLaunchKernelGGL(vps_solve_kernel, dim3(B), dim3(NTHR), 0, stream,
                           t_arr, x_arr, m0, c0, (const uint4*)d_ws, out);
    } else {
        hipLaunchKernelGGL(vps_cg_kernel, dim3(B), dim3(NTHR), 0, stream,
                           t_arr, x_arr, m0, c0, out);
    }
}